// Round 8
// baseline (102.667 us; speedup 1.0000x reference)
//
#include <hip/hip_runtime.h>

// VNCMDLoss: dynamic-queue masked multi-reduction, two kernels.
//  0 recon_real  (B,T)   f32      4 arrays x 8 MiB
//  1 recon_imag  (B,T)   f32
//  2 target_real (B,T)   f32
//  3 target_imag (B,T)   f32
//  4 eIF         (B,N,T) f32      64 MiB (masked rows skipped entirely)
//  5 target_if   (B,N,T) f32      64 MiB (masked rows skipped entirely)
//  6 mode_mask   (B,N)   i32
// Output: 4 x f32: total_loss, recon_loss, if_loss, smooth_loss
//
// Lessons encoded:
//  - R1->R2: FP64 atomicAdd = contended CAS loop (2x). (uint atomicAdd ticket
//    is a native HW RMW -- different beast, ~3.5k ops total, negligible.)
//  - R3: __threadfence+ticket FENCE fusion => L2 writeback per block on
//    non-coherent XCD L2s => 6x. Kernel boundary IS the sync; never fence.
//  - R4: single-WAVE finalize = latency-serialized. Finalize = 1024 threads.
//  - R6: >8-deep load batches under a 64-VGPR cap => scratch spills
//    (WRITE_SIZE 6.2MB). Keep batches at 8 loads.
//  - R6/R7: runtime invariant to data residency + full occupancy barely helped
//    => STATIC MASK IMBALANCE: slowest CU owns ~2x mean bytes. This round:
//    dynamic ticket queue, 5120 uniform 8-load units, blocks self-balance.
//    Determinism: ws[unit] is a pure function of unit data regardless of which
//    block pops it; finalize sums units in fixed order, skips masked slots.

namespace {
constexpr int    kB = 8;
constexpr int    kN = 8;
constexpr int    kT = 262144;
constexpr long long kBT  = (long long)kB * kT;        // 2,097,152
constexpr long long kBNT = (long long)kB * kN * kT;   // 16,777,216

constexpr int THREADS     = 256;
constexpr int GRID        = 2048;    // 8 blocks/CU, full wave slots
constexpr int RECON_UNITS = 1024;    // 512 float4/array per unit (8 loads/thr)
constexpr int IF_SEGS     = 64;      // 1024 float4 per segment (8 loads/thr)
constexpr int IF_UNITS    = kB * kN * IF_SEGS;        // 4096
constexpr int TOTAL_UNITS = RECON_UNITS + IF_UNITS;   // 5120

constexpr int WS_DOUBLES  = 2 * TOTAL_UNITS;          // partials: 80 KiB

constexpr double LAMBDA_IF     = 0.5;
constexpr double LAMBDA_SMOOTH = 0.1;
}

__device__ __forceinline__ float sq(float x) { return x * x; }

__global__ __launch_bounds__(THREADS, 8)
void vncmd_main_kernel(const float* __restrict__ rr, const float* __restrict__ ri,
                       const float* __restrict__ tr, const float* __restrict__ ti,
                       const float* __restrict__ eIF, const float* __restrict__ tIF,
                       const int* __restrict__ mask, double* __restrict__ ws,
                       unsigned int* __restrict__ qctr) {
    const int tid  = threadIdx.x;
    const int lane = tid & 63;
    const int wid  = tid >> 6;

    __shared__ int    smask[kB * kN];
    __shared__ int    s_cur, s_next;
    __shared__ double lds[4][2];

    if (tid < kB * kN) smask[tid] = mask[tid];
    if (tid == 0) s_cur = (int)atomicAdd(qctr, 1u);
    __syncthreads();
    int u = s_cur;

    while (u < TOTAL_UNITS) {
        if (tid == 0) s_next = (int)atomicAdd(qctr, 1u);  // prefetch next ticket

        float p = 0.f, q = 0.f;
        bool do_store = true;

        if (u < RECON_UNITS) {
            // ---- recon unit: 2 float4/thread/array, coalesced (8 loads) ----
            const float4* rr4 = (const float4*)rr;
            const float4* tr4 = (const float4*)tr;
            const float4* ri4 = (const float4*)ri;
            const float4* ti4 = (const float4*)ti;
            const int v0 = u * 512 + tid, v1 = v0 + 256;
            float4 x0 = rr4[v0], x1 = rr4[v1], y0 = tr4[v0], y1 = tr4[v1];
            float4 m0 = ri4[v0], m1 = ri4[v1], w0 = ti4[v0], w1 = ti4[v1];
            p = sq(x0.x - y0.x) + sq(x0.y - y0.y) + sq(x0.z - y0.z) + sq(x0.w - y0.w)
              + sq(x1.x - y1.x) + sq(x1.y - y1.y) + sq(x1.z - y1.z) + sq(x1.w - y1.w);
            q = sq(m0.x - w0.x) + sq(m0.y - w0.y) + sq(m0.z - w0.z) + sq(m0.w - w0.w)
              + sq(m1.x - w1.x) + sq(m1.y - w1.y) + sq(m1.z - w1.z) + sq(m1.w - w1.w);
        } else {
            // ---- IF unit: (row, seg); 4 e-loads + 4 t-loads, coalesced ----
            const int iu  = u - RECON_UNITS;
            const int row = iu >> 6;
            if (smask[row] == 1) {
                const float4* e4 = (const float4*)(eIF + (size_t)row * kT);
                const float4* t4 = (const float4*)(tIF + (size_t)row * kT);
                constexpr int VPR = kT / 4;          // 65536 vectors per row
                const int base = (iu & (IF_SEGS - 1)) * 1024 + tid;
                const int b0 = base, b1 = base + 256, b2 = base + 512, b3 = base + 768;
                const bool l63 = (lane == 63);

                float4 e0 = e4[b0], e1 = e4[b1], e2 = e4[b2], e3 = e4[b3];
                float4 q0 = t4[b0], q1 = t4[b1], q2 = t4[b2], q3 = t4[b3];
                float n0 = 0.f, n1 = 0.f, n2 = 0.f, n3 = 0.f;
                if (l63) {                            // wave-edge boundary scalars
                    n0 = e4[b0 + 1].x;
                    n1 = e4[b1 + 1].x;
                    n2 = e4[b2 + 1].x;
                    n3 = (b3 + 1 < VPR) ? e4[b3 + 1].x : e3.w;   // row end -> 0 term
                }
                p = sq(e0.x - q0.x) + sq(e0.y - q0.y) + sq(e0.z - q0.z) + sq(e0.w - q0.w)
                  + sq(e1.x - q1.x) + sq(e1.y - q1.y) + sq(e1.z - q1.z) + sq(e1.w - q1.w)
                  + sq(e2.x - q2.x) + sq(e2.y - q2.y) + sq(e2.z - q2.z) + sq(e2.w - q2.w)
                  + sq(e3.x - q3.x) + sq(e3.y - q3.y) + sq(e3.z - q3.z) + sq(e3.w - q3.w);
                q = sq(e0.y - e0.x) + sq(e0.z - e0.y) + sq(e0.w - e0.z)
                  + sq(e1.y - e1.x) + sq(e1.z - e1.y) + sq(e1.w - e1.z)
                  + sq(e2.y - e2.x) + sq(e2.z - e2.y) + sq(e2.w - e2.z)
                  + sq(e3.y - e3.x) + sq(e3.z - e3.y) + sq(e3.w - e3.z);
                float s0 = __shfl_down(e0.x, 1, 64);
                float s1 = __shfl_down(e1.x, 1, 64);
                float s2 = __shfl_down(e2.x, 1, 64);
                float s3 = __shfl_down(e3.x, 1, 64);
                if (l63) { s0 = n0; s1 = n1; s2 = n2; s3 = n3; }
                q += sq(s0 - e0.w) + sq(s1 - e1.w) + sq(s2 - e2.w) + sq(s3 - e3.w);
            } else {
                do_store = false;                     // slot never written; finalize skips
            }
        }

        // ---- per-unit block reduction (uniform across block) ----
        double dp = (double)p, dq = (double)q;
        #pragma unroll
        for (int o = 32; o > 0; o >>= 1) {
            dp += __shfl_down(dp, o, 64);
            dq += __shfl_down(dq, o, 64);
        }
        if (lane == 0) { lds[wid][0] = dp; lds[wid][1] = dq; }
        __syncthreads();                              // lds + s_next visible
        if (tid == 0 && do_store) {
            ws[2 * u]     = lds[0][0] + lds[1][0] + lds[2][0] + lds[3][0];
            ws[2 * u + 1] = lds[0][1] + lds[1][1] + lds[2][1] + lds[3][1];
        }
        const int un = s_next;
        __syncthreads();                              // protect lds/s_next reuse
        u = un;
    }
}

// 1024-thread finalize: fixed-order sum of unit partials; masked slots skipped.
__global__ __launch_bounds__(1024)
void finalize_kernel(const double* __restrict__ ws,
                     const int* __restrict__ mask,
                     float* __restrict__ out) {
    const int tid  = threadIdx.x;
    const int lane = tid & 63;
    const int wid  = tid >> 6;            // 16 waves

    double s0 = ws[2 * tid];              // recon units: exactly 1024
    double s1 = ws[2 * tid + 1];
    double s2 = 0.0, s3 = 0.0;
    #pragma unroll
    for (int k = 0; k < IF_UNITS / 1024; ++k) {
        const int iu  = tid + 1024 * k;
        const int row = iu >> 6;
        if (mask[row] == 1) {
            s2 += ws[2 * (RECON_UNITS + iu)];
            s3 += ws[2 * (RECON_UNITS + iu) + 1];
        }
    }
    #pragma unroll
    for (int o = 32; o > 0; o >>= 1) {
        s0 += __shfl_down(s0, o, 64);
        s1 += __shfl_down(s1, o, 64);
        s2 += __shfl_down(s2, o, 64);
        s3 += __shfl_down(s3, o, 64);
    }
    __shared__ double lds[16][4];
    if (lane == 0) { lds[wid][0] = s0; lds[wid][1] = s1; lds[wid][2] = s2; lds[wid][3] = s3; }
    __syncthreads();
    if (tid == 0) {
        double t0 = 0.0, t1 = 0.0, t2 = 0.0, t3 = 0.0;
        #pragma unroll
        for (int i = 0; i < 16; ++i) {
            t0 += lds[i][0]; t1 += lds[i][1]; t2 += lds[i][2]; t3 += lds[i][3];
        }
        int c = 0;
        #pragma unroll
        for (int i = 0; i < kB * kN; ++i) c += (mask[i] == 1);
        double count = (double)c;
        double recon = t0 / (double)kBT + t1 / (double)kBT;
        double ifl   = t2 / (double)kBNT;
        double denom = (count > 1.0 ? count : 1.0) * (double)(kT - 1);
        double smooth = t3 / denom;
        double total = recon + LAMBDA_IF * ifl + (count > 0.0 ? LAMBDA_SMOOTH * smooth : 0.0);
        out[0] = (float)total;
        out[1] = (float)recon;
        out[2] = (float)ifl;
        out[3] = (float)smooth;
    }
}

extern "C" void kernel_launch(void* const* d_in, const int* in_sizes, int n_in,
                              void* d_out, int out_size, void* d_ws, size_t ws_size,
                              hipStream_t stream) {
    const float* rr  = (const float*)d_in[0];
    const float* ri  = (const float*)d_in[1];
    const float* tr  = (const float*)d_in[2];
    const float* ti  = (const float*)d_in[3];
    const float* eIF = (const float*)d_in[4];
    const float* tIF = (const float*)d_in[5];
    const int*   msk = (const int*)d_in[6];
    float* out = (float*)d_out;
    double* ws = (double*)d_ws;
    unsigned int* qctr = (unsigned int*)(ws + WS_DOUBLES);

    hipMemsetAsync(qctr, 0, sizeof(unsigned int), stream);   // graph-legal memset node
    vncmd_main_kernel<<<GRID, THREADS, 0, stream>>>(
        rr, ri, tr, ti, eIF, tIF, msk, ws, qctr);
    finalize_kernel<<<1, 1024, 0, stream>>>(ws, msk, out);
}

// Round 9
// 26.355 us; speedup vs baseline: 3.8956x; 3.8956x over previous
//
#include <hip/hip_runtime.h>

// VNCMDLoss: mask-compacted static-balanced multi-reduction, two kernels.
//  0 recon_real  (B,T)   f32      4 arrays x 8 MiB
//  1 recon_imag  (B,T)   f32
//  2 target_real (B,T)   f32
//  3 target_imag (B,T)   f32
//  4 eIF         (B,N,T) f32      64 MiB (masked rows skipped entirely)
//  5 target_if   (B,N,T) f32      64 MiB (masked rows skipped entirely)
//  6 mode_mask   (B,N)   i32
// Output: 4 x f32: total_loss, recon_loss, if_loss, smooth_loss
//
// Lessons encoded:
//  - R1->R2: FP64 atomicAdd = contended CAS loop (2x). Per-block stores.
//  - R3: __threadfence+ticket fusion => per-block L2 writeback on non-coherent
//    XCD L2s => 6x. Kernel boundary IS the sync; never fence.
//  - R4: single-WAVE finalize = latency-serialized. Finalize = 1024 threads.
//  - R6: >8 loads in flight under 64-VGPR cap => scratch spills. Batch = 8.
//  - R7: full-slot static grid = 24.8us; mask-dependent bytes/block => worst
//    CU ~1.4x mean.
//  - R8: DYNAMIC global-atomic ticket queue = 89us kernel: single cacheline
//    RMW bounces across 8 XCD L2s, ~7k pops serialize on the critical path.
//    NEVER use per-unit global tickets on multi-XCD parts.
//  - R9 (this): balance WITHOUT atomics: mask is 64 bits, so every block
//    compacts active rows itself (one __ballot in wave 0). Work list =
//    1024 recon + 64*A active-IF units, ALL units byte-identical (8 loads/
//    thread). Block b owns units {b, b+2048, b+4096} (<=3), register-
//    accumulated, one reduce+store per block. No memset, no atomics.

namespace {
constexpr int    kB = 8;
constexpr int    kN = 8;
constexpr int    kT = 262144;
constexpr long long kBT  = (long long)kB * kT;        // 2,097,152
constexpr long long kBNT = (long long)kB * kN * kT;   // 16,777,216

constexpr int THREADS     = 256;
constexpr int GRID        = 2048;    // 8 blocks/CU, full wave slots
constexpr int RECON_UNITS = 1024;    // 512 float4/array/unit (8 loads/thread)
constexpr int IF_SEGS     = 64;      // 1024 float4/segment  (8 loads/thread)

constexpr double LAMBDA_IF     = 0.5;
constexpr double LAMBDA_SMOOTH = 0.1;
}

__device__ __forceinline__ float sq(float x) { return x * x; }

__global__ __launch_bounds__(THREADS, 8)
void vncmd_main_kernel(const float* __restrict__ rr, const float* __restrict__ ri,
                       const float* __restrict__ tr, const float* __restrict__ ti,
                       const float* __restrict__ eIF, const float* __restrict__ tIF,
                       const int* __restrict__ mask, double* __restrict__ ws) {
    const int tid  = threadIdx.x;
    const int bid  = blockIdx.x;
    const int lane = tid & 63;
    const int wid  = tid >> 6;

    // ---- prologue: compact active rows (wave 0 only, one ballot) ----
    __shared__ int s_active[kB * kN];
    __shared__ int s_U;                       // total unit count
    if (tid < 64) {
        const int m = mask[tid];
        const unsigned long long bits = __ballot(m == 1);
        const int pos = (int)__popcll(bits & ((1ull << lane) - 1ull));
        if (m == 1) s_active[pos] = lane;
        if (lane == 0) s_U = RECON_UNITS + IF_SEGS * (int)__popcll(bits);
    }
    __syncthreads();
    const int U = s_U;

    // ---- up to 3 byte-identical units, register-accumulated ----
    float a0 = 0.f, a1 = 0.f, a2 = 0.f, a3 = 0.f;
    for (int u = bid; u < U; u += GRID) {
        if (u < RECON_UNITS) {
            // recon unit: 2 float4/thread/array, coalesced (8 loads)
            const float4* rr4 = (const float4*)rr;
            const float4* tr4 = (const float4*)tr;
            const float4* ri4 = (const float4*)ri;
            const float4* ti4 = (const float4*)ti;
            const int v0 = u * 512 + tid, v1 = v0 + 256;
            float4 x0 = rr4[v0], x1 = rr4[v1], y0 = tr4[v0], y1 = tr4[v1];
            float4 m0 = ri4[v0], m1 = ri4[v1], w0 = ti4[v0], w1 = ti4[v1];
            a0 += sq(x0.x - y0.x) + sq(x0.y - y0.y) + sq(x0.z - y0.z) + sq(x0.w - y0.w)
                + sq(x1.x - y1.x) + sq(x1.y - y1.y) + sq(x1.z - y1.z) + sq(x1.w - y1.w);
            a1 += sq(m0.x - w0.x) + sq(m0.y - w0.y) + sq(m0.z - w0.z) + sq(m0.w - w0.w)
                + sq(m1.x - w1.x) + sq(m1.y - w1.y) + sq(m1.z - w1.z) + sq(m1.w - w1.w);
        } else {
            // active-IF unit: row from compacted list; 4 e-loads + 4 t-loads
            const int au  = u - RECON_UNITS;
            const int row = s_active[au >> 6];
            const int seg = au & (IF_SEGS - 1);
            const float4* e4 = (const float4*)(eIF + (size_t)row * kT);
            const float4* t4 = (const float4*)(tIF + (size_t)row * kT);
            constexpr int VPR = kT / 4;       // 65536 vectors per row
            const int base = seg * 1024 + tid;
            const int b0 = base, b1 = base + 256, b2 = base + 512, b3 = base + 768;
            const bool l63 = (lane == 63);

            float4 e0 = e4[b0], e1 = e4[b1], e2 = e4[b2], e3 = e4[b3];
            float4 q0 = t4[b0], q1 = t4[b1], q2 = t4[b2], q3 = t4[b3];
            float n0 = 0.f, n1 = 0.f, n2 = 0.f, n3 = 0.f;
            if (l63) {                         // wave-edge boundary scalars
                n0 = e4[b0 + 1].x;
                n1 = e4[b1 + 1].x;
                n2 = e4[b2 + 1].x;
                n3 = (b3 + 1 < VPR) ? e4[b3 + 1].x : e3.w;   // row end -> 0 term
            }
            a2 += sq(e0.x - q0.x) + sq(e0.y - q0.y) + sq(e0.z - q0.z) + sq(e0.w - q0.w)
                + sq(e1.x - q1.x) + sq(e1.y - q1.y) + sq(e1.z - q1.z) + sq(e1.w - q1.w)
                + sq(e2.x - q2.x) + sq(e2.y - q2.y) + sq(e2.z - q2.z) + sq(e2.w - q2.w)
                + sq(e3.x - q3.x) + sq(e3.y - q3.y) + sq(e3.z - q3.z) + sq(e3.w - q3.w);
            a3 += sq(e0.y - e0.x) + sq(e0.z - e0.y) + sq(e0.w - e0.z)
                + sq(e1.y - e1.x) + sq(e1.z - e1.y) + sq(e1.w - e1.z)
                + sq(e2.y - e2.x) + sq(e2.z - e2.y) + sq(e2.w - e2.z)
                + sq(e3.y - e3.x) + sq(e3.z - e3.y) + sq(e3.w - e3.z);
            float s0 = __shfl_down(e0.x, 1, 64);
            float s1 = __shfl_down(e1.x, 1, 64);
            float s2 = __shfl_down(e2.x, 1, 64);
            float s3 = __shfl_down(e3.x, 1, 64);
            if (l63) { s0 = n0; s1 = n1; s2 = n2; s3 = n3; }
            a3 += sq(s0 - e0.w) + sq(s1 - e1.w) + sq(s2 - e2.w) + sq(s3 - e3.w);
        }
    }

    // ---- single block reduction: 4 partials -> ws[4*bid] (always written) ----
    double d0 = (double)a0, d1 = (double)a1, d2 = (double)a2, d3 = (double)a3;
    #pragma unroll
    for (int o = 32; o > 0; o >>= 1) {
        d0 += __shfl_down(d0, o, 64);
        d1 += __shfl_down(d1, o, 64);
        d2 += __shfl_down(d2, o, 64);
        d3 += __shfl_down(d3, o, 64);
    }
    __shared__ double lds[4][4];
    if (lane == 0) { lds[wid][0] = d0; lds[wid][1] = d1; lds[wid][2] = d2; lds[wid][3] = d3; }
    __syncthreads();
    if (tid == 0) {
        double* dst = ws + 4 * bid;
        dst[0] = lds[0][0] + lds[1][0] + lds[2][0] + lds[3][0];
        dst[1] = lds[0][1] + lds[1][1] + lds[2][1] + lds[3][1];
        dst[2] = lds[0][2] + lds[1][2] + lds[2][2] + lds[3][2];
        dst[3] = lds[0][3] + lds[1][3] + lds[2][3] + lds[3][3];
    }
}

// 1024-thread finalize: reduce 2048 x 4 doubles (64 KB), write the 4 outputs.
__global__ __launch_bounds__(1024)
void finalize_kernel(const double* __restrict__ ws,
                     const int* __restrict__ mask,
                     float* __restrict__ out) {
    const int tid  = threadIdx.x;
    const int lane = tid & 63;
    const int wid  = tid >> 6;            // 16 waves

    const double2* w2 = (const double2*)ws;
    double s0 = 0.0, s1 = 0.0, s2 = 0.0, s3 = 0.0;
    #pragma unroll
    for (int k = 0; k < GRID / 1024; ++k) {
        const int b = k * 1024 + tid;
        double2 p = w2[2 * b], q = w2[2 * b + 1];
        s0 += p.x; s1 += p.y; s2 += q.x; s3 += q.y;
    }
    #pragma unroll
    for (int o = 32; o > 0; o >>= 1) {
        s0 += __shfl_down(s0, o, 64);
        s1 += __shfl_down(s1, o, 64);
        s2 += __shfl_down(s2, o, 64);
        s3 += __shfl_down(s3, o, 64);
    }
    __shared__ double lds[16][4];
    if (lane == 0) { lds[wid][0] = s0; lds[wid][1] = s1; lds[wid][2] = s2; lds[wid][3] = s3; }
    __syncthreads();
    if (tid == 0) {
        double t0 = 0.0, t1 = 0.0, t2 = 0.0, t3 = 0.0;
        #pragma unroll
        for (int i = 0; i < 16; ++i) {
            t0 += lds[i][0]; t1 += lds[i][1]; t2 += lds[i][2]; t3 += lds[i][3];
        }
        int c = 0;
        #pragma unroll
        for (int i = 0; i < kB * kN; ++i) c += (mask[i] == 1);
        double count = (double)c;
        double recon = t0 / (double)kBT + t1 / (double)kBT;
        double ifl   = t2 / (double)kBNT;
        double denom = (count > 1.0 ? count : 1.0) * (double)(kT - 1);
        double smooth = t3 / denom;
        double total = recon + LAMBDA_IF * ifl + (count > 0.0 ? LAMBDA_SMOOTH * smooth : 0.0);
        out[0] = (float)total;
        out[1] = (float)recon;
        out[2] = (float)ifl;
        out[3] = (float)smooth;
    }
}

extern "C" void kernel_launch(void* const* d_in, const int* in_sizes, int n_in,
                              void* d_out, int out_size, void* d_ws, size_t ws_size,
                              hipStream_t stream) {
    const float* rr  = (const float*)d_in[0];
    const float* ri  = (const float*)d_in[1];
    const float* tr  = (const float*)d_in[2];
    const float* ti  = (const float*)d_in[3];
    const float* eIF = (const float*)d_in[4];
    const float* tIF = (const float*)d_in[5];
    const int*   msk = (const int*)d_in[6];
    float* out = (float*)d_out;
    double* ws = (double*)d_ws;

    vncmd_main_kernel<<<GRID, THREADS, 0, stream>>>(
        rr, ri, tr, ti, eIF, tIF, msk, ws);
    finalize_kernel<<<1, 1024, 0, stream>>>(ws, msk, out);
}

// Round 10
// 22.919 us; speedup vs baseline: 4.4795x; 1.1499x over previous
//
#include <hip/hip_runtime.h>

// VNCMDLoss: two-stage masked multi-reduction. R7 structure + non-temporal
// streaming loads + lean finalize.
//  0 recon_real  (B,T)   f32      4 arrays x 8 MiB
//  1 recon_imag  (B,T)   f32
//  2 target_real (B,T)   f32
//  3 target_imag (B,T)   f32
//  4 eIF         (B,N,T) f32      64 MiB (masked rows skipped entirely)
//  5 target_if   (B,N,T) f32      64 MiB (masked rows skipped entirely)
//  6 mode_mask   (B,N)   i32
// Output: 4 x f32: total_loss, recon_loss, if_loss, smooth_loss
//
// Lessons encoded:
//  - R1->R2: FP64 atomicAdd = contended CAS loop (2x). Per-block stores.
//  - R3: __threadfence+ticket fusion => per-block L2 writeback on non-coherent
//    XCD L2s => 6x. Kernel boundary IS the sync; never fence.
//  - R4: single-WAVE finalize = latency-serialized. Finalize >= 512 threads.
//  - R6: >8 loads in flight under VGPR cap => scratch spills. Batch = 8.
//  - R8: dynamic global-atomic ticket = cacheline bouncing across 8 XCD L2s,
//    89us. Never per-unit global tickets.
//  - R7 vs R9: mask imbalance does NOT limit (worst-20-load R7 beat balanced-
//    12-load R9). All structures land ~25us: main kernel ~19us = 84% of
//    streaming roofline; rest is finalize + graph overhead.
//  - R10 (this): R7 exact structure, minus LDS mask staging (block-uniform
//    scalar load instead), plus non-temporal loads (read-once streams),
//    float4 partials, 512-thread finalize.

namespace {
constexpr int    kB = 8;
constexpr int    kN = 8;
constexpr int    kT = 262144;
constexpr long long kBT  = (long long)kB * kT;        // 2,097,152
constexpr long long kBNT = (long long)kB * kN * kT;   // 16,777,216

constexpr int THREADS  = 256;
constexpr int GRID     = 2048;      // 8 blocks/CU, full wave slots
constexpr int IF_SEGS  = 64;        // 1024 float4 per segment (8 loads/thread)

constexpr double LAMBDA_IF     = 0.5;
constexpr double LAMBDA_SMOOTH = 0.1;
}

typedef float vf4 __attribute__((ext_vector_type(4)));

__device__ __forceinline__ float sq(float x) { return x * x; }

// Non-temporal 16B load: read-once stream, skip cache allocation.
__device__ __forceinline__ vf4 ntld(const vf4* p) {
    return __builtin_nontemporal_load(p);
}

// recon unit u in [0,2048): one float4 per thread per array (4 nt loads).
__device__ __forceinline__ void recon_accum(int u, int tid,
                                            const vf4* __restrict__ rr4,
                                            const vf4* __restrict__ tr4,
                                            const vf4* __restrict__ ri4,
                                            const vf4* __restrict__ ti4,
                                            float& a0, float& a1) {
    const int v = u * THREADS + tid;          // [0, 524288)
    vf4 x = ntld(rr4 + v), y = ntld(tr4 + v);
    vf4 m = ntld(ri4 + v), w = ntld(ti4 + v);
    a0 += sq(x.x - y.x) + sq(x.y - y.y) + sq(x.z - y.z) + sq(x.w - y.w);
    a1 += sq(m.x - w.x) + sq(m.y - w.y) + sq(m.z - w.z) + sq(m.w - w.w);
}

// IF unit iu in [0,4096): (row, seg); masked rows contribute nothing.
__device__ __forceinline__ void if_accum(int iu, int tid,
                                         const float* __restrict__ eIF,
                                         const float* __restrict__ tIF,
                                         const int* __restrict__ mask,
                                         float& a2, float& a3) {
    const int row = iu >> 6;                  // block-uniform -> scalar load
    if (mask[row] != 1) return;
    const int seg = iu & (IF_SEGS - 1);

    const vf4* e4 = (const vf4*)(eIF + (size_t)row * kT);
    const vf4* t4 = (const vf4*)(tIF + (size_t)row * kT);
    constexpr int VPR = kT / 4;               // 65536 vectors per row
    const int base = seg * 1024 + tid;
    const int b0 = base, b1 = base + 256, b2 = base + 512, b3 = base + 768;
    const bool l63 = ((tid & 63) == 63);

    // 8 nt loads issued back-to-back (32 data VGPRs)
    vf4 e0 = ntld(e4 + b0), e1 = ntld(e4 + b1), e2 = ntld(e4 + b2), e3 = ntld(e4 + b3);
    vf4 q0 = ntld(t4 + b0), q1 = ntld(t4 + b1), q2 = ntld(t4 + b2), q3 = ntld(t4 + b3);
    float n0 = 0.f, n1 = 0.f, n2 = 0.f, n3 = 0.f;
    if (l63) {                                // wave-edge boundary scalars (cached)
        n0 = e4[b0 + 1].x;
        n1 = e4[b1 + 1].x;
        n2 = e4[b2 + 1].x;
        n3 = (b3 + 1 < VPR) ? e4[b3 + 1].x : e3.w;   // row end -> zero term
    }
    a2 += sq(e0.x - q0.x) + sq(e0.y - q0.y) + sq(e0.z - q0.z) + sq(e0.w - q0.w)
        + sq(e1.x - q1.x) + sq(e1.y - q1.y) + sq(e1.z - q1.z) + sq(e1.w - q1.w)
        + sq(e2.x - q2.x) + sq(e2.y - q2.y) + sq(e2.z - q2.z) + sq(e2.w - q2.w)
        + sq(e3.x - q3.x) + sq(e3.y - q3.y) + sq(e3.z - q3.z) + sq(e3.w - q3.w);
    a3 += sq(e0.y - e0.x) + sq(e0.z - e0.y) + sq(e0.w - e0.z)
        + sq(e1.y - e1.x) + sq(e1.z - e1.y) + sq(e1.w - e1.z)
        + sq(e2.y - e2.x) + sq(e2.z - e2.y) + sq(e2.w - e2.z)
        + sq(e3.y - e3.x) + sq(e3.z - e3.y) + sq(e3.w - e3.z);
    float s0 = __shfl_down(e0.x, 1, 64);
    float s1 = __shfl_down(e1.x, 1, 64);
    float s2 = __shfl_down(e2.x, 1, 64);
    float s3 = __shfl_down(e3.x, 1, 64);
    if (l63) { s0 = n0; s1 = n1; s2 = n2; s3 = n3; }
    a3 += sq(s0 - e0.w) + sq(s1 - e1.w) + sq(s2 - e2.w) + sq(s3 - e3.w);
}

__global__ __launch_bounds__(THREADS, 8)
void vncmd_main_kernel(const float* __restrict__ rr, const float* __restrict__ ri,
                       const float* __restrict__ tr, const float* __restrict__ ti,
                       const float* __restrict__ eIF, const float* __restrict__ tIF,
                       const int* __restrict__ mask, float* __restrict__ ws) {
    const int tid  = threadIdx.x;
    const int bid  = blockIdx.x;
    const int lane = tid & 63;
    const int wid  = tid >> 6;

    float a0 = 0.f, a1 = 0.f, a2 = 0.f, a3 = 0.f;
    recon_accum(bid, tid, (const vf4*)rr, (const vf4*)tr,
                (const vf4*)ri, (const vf4*)ti, a0, a1);
    if_accum(bid,        tid, eIF, tIF, mask, a2, a3);
    if_accum(bid + 2048, tid, eIF, tIF, mask, a2, a3);

    // ---- single block reduction (fp32; partial ~1e5, rel err ~6e-8) ----
    #pragma unroll
    for (int o = 32; o > 0; o >>= 1) {
        a0 += __shfl_down(a0, o, 64);
        a1 += __shfl_down(a1, o, 64);
        a2 += __shfl_down(a2, o, 64);
        a3 += __shfl_down(a3, o, 64);
    }
    __shared__ float lds[4][4];
    if (lane == 0) { lds[wid][0] = a0; lds[wid][1] = a1; lds[wid][2] = a2; lds[wid][3] = a3; }
    __syncthreads();
    if (tid == 0) {
        vf4 r;
        r.x = lds[0][0] + lds[1][0] + lds[2][0] + lds[3][0];
        r.y = lds[0][1] + lds[1][1] + lds[2][1] + lds[3][1];
        r.z = lds[0][2] + lds[1][2] + lds[2][2] + lds[3][2];
        r.w = lds[0][3] + lds[1][3] + lds[2][3] + lds[3][3];
        ((vf4*)ws)[bid] = r;
    }
}

// 512-thread finalize: reduce 2048 float4 partials (32 KB) in double.
__global__ __launch_bounds__(512)
void finalize_kernel(const float* __restrict__ ws,
                     const int* __restrict__ mask,
                     float* __restrict__ out) {
    const int tid  = threadIdx.x;
    const int lane = tid & 63;
    const int wid  = tid >> 6;            // 8 waves

    const vf4* w4 = (const vf4*)ws;
    double s0 = 0.0, s1 = 0.0, s2 = 0.0, s3 = 0.0;
    #pragma unroll
    for (int k = 0; k < GRID / 512; ++k) {
        vf4 p = w4[k * 512 + tid];
        s0 += p.x; s1 += p.y; s2 += p.z; s3 += p.w;
    }
    #pragma unroll
    for (int o = 32; o > 0; o >>= 1) {
        s0 += __shfl_down(s0, o, 64);
        s1 += __shfl_down(s1, o, 64);
        s2 += __shfl_down(s2, o, 64);
        s3 += __shfl_down(s3, o, 64);
    }
    __shared__ double lds[8][4];
    if (lane == 0) { lds[wid][0] = s0; lds[wid][1] = s1; lds[wid][2] = s2; lds[wid][3] = s3; }
    __syncthreads();
    if (tid == 0) {
        double t0 = 0.0, t1 = 0.0, t2 = 0.0, t3 = 0.0;
        #pragma unroll
        for (int i = 0; i < 8; ++i) {
            t0 += lds[i][0]; t1 += lds[i][1]; t2 += lds[i][2]; t3 += lds[i][3];
        }
        int c = 0;
        #pragma unroll
        for (int i = 0; i < kB * kN; ++i) c += (mask[i] == 1);
        double count = (double)c;
        double recon = t0 / (double)kBT + t1 / (double)kBT;
        double ifl   = t2 / (double)kBNT;
        double denom = (count > 1.0 ? count : 1.0) * (double)(kT - 1);
        double smooth = t3 / denom;
        double total = recon + LAMBDA_IF * ifl + (count > 0.0 ? LAMBDA_SMOOTH * smooth : 0.0);
        out[0] = (float)total;
        out[1] = (float)recon;
        out[2] = (float)ifl;
        out[3] = (float)smooth;
    }
}

extern "C" void kernel_launch(void* const* d_in, const int* in_sizes, int n_in,
                              void* d_out, int out_size, void* d_ws, size_t ws_size,
                              hipStream_t stream) {
    const float* rr  = (const float*)d_in[0];
    const float* ri  = (const float*)d_in[1];
    const float* tr  = (const float*)d_in[2];
    const float* ti  = (const float*)d_in[3];
    const float* eIF = (const float*)d_in[4];
    const float* tIF = (const float*)d_in[5];
    const int*   msk = (const int*)d_in[6];
    float* out = (float*)d_out;
    float* ws  = (float*)d_ws;

    vncmd_main_kernel<<<GRID, THREADS, 0, stream>>>(
        rr, ri, tr, ti, eIF, tIF, msk, ws);
    finalize_kernel<<<1, 512, 0, stream>>>(ws, msk, out);
}